// Round 14
// baseline (1321.462 us; speedup 1.0000x reference)
//
#include <hip/hip_runtime.h>

typedef unsigned short u16;
typedef unsigned int   u32;
typedef __attribute__((ext_vector_type(2))) u32  u32x2;
typedef __attribute__((ext_vector_type(4))) u32  u32x4;
typedef __attribute__((ext_vector_type(8))) __bf16 bf16x8;
typedef __attribute__((ext_vector_type(4))) float  f32x4;

#define NN 20000
#define NE 320000
#define XD 131
#define F  128
#define MD 64
#define H1 514
#define H1P 544
#define NCH 17

#define GAS __attribute__((address_space(1)))
#define LAS __attribute__((address_space(3)))
#define LGKM0 asm volatile("s_waitcnt lgkmcnt(0)" ::: "memory")

__device__ __forceinline__ float silu(float a) {
    float e = __expf(-a);
    return a * __builtin_amdgcn_rcpf(1.0f + e);
}

__device__ __forceinline__ u16 f2bf(float f) {   // fp32 -> bf16 RNE
    u32 u = __builtin_bit_cast(u32, f);
    return (u16)((u + 0x7FFFu + ((u >> 16) & 1u)) >> 16);
}
__device__ __forceinline__ u16 bfc(float f) { return __builtin_bit_cast(u16, (__bf16)f); }
__device__ __forceinline__ u32 pk2(float a, float b) {
    return (u32)bfc(a) | ((u32)bfc(b) << 16);
}
__device__ __forceinline__ float blo(u32 u) { return __builtin_bit_cast(float, u << 16); }
__device__ __forceinline__ float bhi(u32 u) { return __builtin_bit_cast(float, u & 0xFFFF0000u); }
__device__ __forceinline__ bf16x8 mk8(u32 a, u32 b, u32 c, u32 d) {
    u32x4 t = {a, b, c, d};
    return __builtin_bit_cast(bf16x8, t);
}
__device__ __forceinline__ f32x4 mfma16(bf16x8 a, bf16x8 b, f32x4 c) {
    return __builtin_amdgcn_mfma_f32_16x16x32_bf16(a, b, c, 0, 0, 0);
}

// ---------------- weight prep ----------------

// w1p[l][n<1088][k<128] 256B rows. n<544: W1a rows (Ya cols); n>=544: W1b rows (Yb cols).
// eb1p[l][544] f32 bias (folded into Ya), w1lf[l][544] f32 last-row weights.
__global__ void prep_w1n(const float* __restrict__ ew1, const float* __restrict__ eb1,
                         u16* __restrict__ w1p, float* __restrict__ eb1p, float* __restrict__ w1lf) {
    int i = blockIdx.x * 256 + threadIdx.x;
    if (i >= 3 * 1088 * 128) return;
    int k = i & 127;
    int n = (i >> 7) % 1088;
    int l = (i >> 7) / 1088;
    float v;
    if (n < H1P) v = (n < H1) ? ew1[(size_t)l * 257 * H1 + (size_t)k * H1 + n] : 0.f;
    else { int nn = n - H1P; v = (nn < H1) ? ew1[(size_t)l * 257 * H1 + (size_t)(128 + k) * H1 + nn] : 0.f; }
    w1p[(size_t)(l * 1088 + n) * 128 + k] = f2bf(v);
    if (k == 0 && n < H1P) {
        eb1p[l * H1P + n] = (n < H1) ? eb1[l * H1 + n] : 0.f;
        w1lf[l * H1P + n] = (n < H1) ? ew1[(size_t)l * 257 * H1 + (size_t)256 * H1 + n] : 0.f;
    }
}

__global__ void prep_w2(const float* __restrict__ ew2, u16* __restrict__ w2b) {
    int i = blockIdx.x * 256 + threadIdx.x;
    if (i >= 3 * 64 * H1P) return;
    int k = i % H1P;
    int n = (i / H1P) & 63;
    int l = i / (H1P * 64);
    float v = (k < H1) ? ew2[(size_t)l * H1 * 64 + (size_t)k * 64 + n] : 0.f;
    w2b[(size_t)(l * 64 + n) * H1P + k] = f2bf(v);
}

__global__ void prep_cw1(const float* __restrict__ cw1, u16* __restrict__ cw1b) {
    int i = blockIdx.x * 256 + threadIdx.x;
    if (i >= 3 * 256 * 64) return;
    int k = i & 63;
    int n = (i >> 6) & 255;
    int l = i >> 14;
    cw1b[(size_t)l * 16384 + n * 64 + k] = f2bf(cw1[(size_t)l * 16384 + k * 256 + n]);
}

__global__ void prep_nw1(const float* __restrict__ nw1, u16* __restrict__ nw1b) {
    int i = blockIdx.x * 256 + threadIdx.x;
    if (i >= 3 * 256 * 192) return;
    int k = i % 192;
    int n = (i / 192) & 255;
    int l = i / (192 * 256);
    nw1b[(size_t)(l * 256 + n) * 192 + k] = f2bf(nw1[(size_t)l * 192 * 256 + (size_t)k * 256 + n]);
}

__global__ void prep_nw2(const float* __restrict__ nw2, u16* __restrict__ nw2b) {
    int i = blockIdx.x * 256 + threadIdx.x;
    if (i >= 3 * 128 * 256) return;
    int k = i & 255;
    int n = (i >> 8) & 127;
    int l = i >> 15;
    nw2b[(size_t)(l * 128 + n) * 256 + k] = f2bf(nw2[(size_t)l * 256 * 128 + (size_t)k * 128 + n]);
}

__global__ void x2bf(const float* __restrict__ xc, u32* __restrict__ xbf) {
    int i = blockIdx.x * 256 + threadIdx.x;   // NN*64
    if (i >= NN * 64) return;
    const int node = i >> 6, p = i & 63;
    const float a = xc[(size_t)node * XD + 3 + 2 * p];
    const float b = xc[(size_t)node * XD + 4 + 2 * p];
    xbf[(size_t)node * 64 + p] = pk2(a, b);
}

// ---------------- Y precompute (Ya half only): Y[v][0:544] = X@W1a + b ----------------
// grid (157, 2): x = node-tile (128 nodes, 4 waves x 32), y = 17 col-tiles each

__global__ __launch_bounds__(256, 4) void ygemm(
    const u16* __restrict__ xbf, const char* __restrict__ w1p,
    const float* __restrict__ eb1p, u16* __restrict__ Y)
{
    const int tid = threadIdx.x;
    const int w = tid >> 6, l = tid & 63, lg = l >> 4, lc = l & 15;
    const int nb0 = blockIdx.x * 128 + w * 32;
    const int n0 = nb0 + lc, n1 = nb0 + 16 + lc;
    const bool v0 = n0 < NN, v1 = n1 < NN;
    const int m0 = v0 ? n0 : NN - 1, m1 = v1 ? n1 : NN - 1;

    bf16x8 BF[2][4];
    #pragma unroll
    for (int kt = 0; kt < 4; ++kt) {
        BF[0][kt] = *(const bf16x8*)((const char*)xbf + (size_t)m0 * 256 + kt * 64 + lg * 16);
        BF[1][kt] = *(const bf16x8*)((const char*)xbf + (size_t)m1 * 256 + kt * 64 + lg * 16);
    }

    const int t0 = blockIdx.y * 17;
    #pragma unroll 1
    for (int t = t0; t < t0 + 17; ++t) {
        bf16x8 AW[4];
        #pragma unroll
        for (int kt = 0; kt < 4; ++kt)
            AW[kt] = *(const bf16x8*)(w1p + (size_t)(t * 16 + lc) * 256 + kt * 64 + lg * 16);
        const int cb = t * 16 + lg * 4;
        f32x4 binit = *(const f32x4*)(eb1p + cb);
        f32x4 c0 = binit, c1 = binit;
        #pragma unroll
        for (int kt = 0; kt < 4; ++kt) {
            c0 = mfma16(AW[kt], BF[0][kt], c0);
            c1 = mfma16(AW[kt], BF[1][kt], c1);
        }
        u32x2 p0, p1;
        p0[0] = pk2(c0[0], c0[1]); p0[1] = pk2(c0[2], c0[3]);
        p1[0] = pk2(c1[0], c1[1]); p1[1] = pk2(c1[2], c1[3]);
        if (v0) *(u32x2*)(Y + (size_t)m0 * H1P + cb) = p0;
        if (v1) *(u32x2*)(Y + (size_t)m1 * H1P + cb) = p1;
    }
}

// ---------------- CSR build + edge sort (once per launch; graph constant) ----------------

__global__ void csr_hist(const int* __restrict__ eidx, int* __restrict__ cnt) {
    int e = blockIdx.x * 256 + threadIdx.x;
    if (e < NE) atomicAdd(&cnt[eidx[NE + e]], 1);
}

__global__ void csr_scan(const int* __restrict__ cnt, int* __restrict__ rowp) {
    __shared__ int ps[1024];
    const int t = threadIdx.x;
    const int base = t * 20;
    int loc[20];
    int s = 0;
    #pragma unroll
    for (int i = 0; i < 20; ++i) {
        const int idx = base + i;
        const int c = (idx < NN) ? cnt[idx] : 0;
        loc[i] = s;
        s += c;
    }
    ps[t] = s;
    __syncthreads();
    for (int off = 1; off < 1024; off <<= 1) {
        int v = (t >= off) ? ps[t - off] : 0;
        __syncthreads();
        ps[t] += v;
        __syncthreads();
    }
    const int segbase = (t > 0) ? ps[t - 1] : 0;
    #pragma unroll
    for (int i = 0; i < 20; ++i) {
        const int idx = base + i;
        if (idx < NN) rowp[idx] = segbase + loc[i];
    }
    if (t == 1023) rowp[NN] = ps[1023];
}

__global__ void csr_fill(const int* __restrict__ eidx, const int* __restrict__ rowp,
                         int* __restrict__ fill, int* __restrict__ eids) {
    int e = blockIdx.x * 256 + threadIdx.x;
    if (e >= NE) return;
    const int d = eidx[NE + e];
    const int pos = atomicAdd(&fill[d], 1);
    eids[rowp[d] + pos] = e;
}

__global__ void esort(const int* __restrict__ eidx, const int* __restrict__ eids,
                      int* __restrict__ esrc, int* __restrict__ edst) {
    int j = blockIdx.x * 256 + threadIdx.x;
    if (j >= NE) return;
    const int e = eids[j];
    esrc[j] = eidx[e];
    edst[j] = eidx[NE + e];
}

// ---------------- segment sums over contiguous sorted rows ----------------

__global__ __launch_bounds__(256, 4) void reduce_mi(
    const u16* __restrict__ gmij, const float* __restrict__ gmh,
    const int* __restrict__ rowp, float* __restrict__ m_i, float* __restrict__ mh) {
    const int tid = threadIdx.x;
    const int n = blockIdx.x * 8 + (tid >> 5);
    const int t = tid & 31;
    if (n >= NN) return;
    const int b = rowp[n], e = rowp[n + 1];
    float a0 = 0.f, a1 = 0.f;
    for (int j = b; j < e; ++j) {
        const u32 v = *(const u32*)(gmij + (size_t)j * 64 + t * 2);
        a0 += blo(v);
        a1 += bhi(v);
    }
    m_i[(size_t)n * 64 + 2 * t]     = a0;
    m_i[(size_t)n * 64 + 2 * t + 1] = a1;
    if (t < 3) {
        float m = 0.f;
        for (int j = b; j < e; ++j) m += gmh[(size_t)j * 4 + t];
        mh[n * 3 + t] = m;
    }
}

// ---------------- edge kernel v3: Ya gather + on-the-fly Yb via MFMA ----------------
// 128 edges/block, 4 waves x 32 edges. Per chunk (32 h-cols):
//   c1 init = Ya[dst] + rd*w_last  (8B dst-sorted gather, L2-hot)
//   c1 += W1b_chunk(A, L2) x xbf[src](B, regs)  -> full pre-activation via MFMA
//   h = silu(c1) -> HT repack -> MLP2 accumulate.
// Random traffic = xbf[src] prologue only (256B/edge).

__global__ __launch_bounds__(256, 3) void edge_mfma3(
    const float* __restrict__ x, const u16* __restrict__ Y, const u16* __restrict__ xbf,
    const int* __restrict__ esrc, const int* __restrict__ edst,
    const char* __restrict__ w1bh, const float* __restrict__ w1lf,
    const char* __restrict__ w2b, const float* __restrict__ eb2,
    const char* __restrict__ cw1b, const float* __restrict__ cb1,
    const float* __restrict__ cw2, const float* __restrict__ cb2,
    u16* __restrict__ gmij, float* __restrict__ gmh)
{
    // [0,10240): HT per-wave 2560B; [10240,27648): MJ per-wave 4352B; [27648,29696): RDS
    __shared__ __align__(16) char LDS[29696];
    const int tid = threadIdx.x;
    const int w = tid >> 6, l = tid & 63, lg = l >> 4, lc = l & 15;
    const int ebase = blockIdx.x * 128 + w * 32;
    char*  HT  = LDS + w * 2560;
    char*  MJ  = LDS + 10240 + w * 4352;
    float* RDS = (float*)(LDS + 27648);

    // per-edge geometry (lanes l<32, wave-private rows; LGKM-only sync)
    if (l < 32) {
        const int e = ebase + l;
        const int s = esrc[e], d = edst[e];
        const float ax = x[(size_t)s * XD + 0] - x[(size_t)d * XD + 0];
        const float ay = x[(size_t)s * XD + 1] - x[(size_t)d * XD + 1];
        const float az = x[(size_t)s * XD + 2] - x[(size_t)d * XD + 2];
        f32x4 v = {ax, ay, az, ax * ax + ay * ay + az * az};
        *(f32x4*)(RDS + (w * 32 + l) * 4) = v;
    }
    const int s0 = esrc[ebase + lc],      d0 = edst[ebase + lc];
    const int s1 = esrc[ebase + 16 + lc], d1 = edst[ebase + 16 + lc];
    LGKM0;
    const float rd0 = RDS[(w * 32 + lc) * 4 + 3];
    const float rd1 = RDS[(w * 32 + 16 + lc) * 4 + 3];

    // xbf[src] B-fragments, held whole kernel (the only random gather; 256B/edge)
    bf16x8 BX[2][4];
    #pragma unroll
    for (int kt = 0; kt < 4; ++kt) {
        BX[0][kt] = *(const bf16x8*)((const char*)xbf + (size_t)s0 * 256 + kt * 64 + lg * 16);
        BX[1][kt] = *(const bf16x8*)((const char*)xbf + (size_t)s1 * 256 + kt * 64 + lg * 16);
    }

    f32x4 c2[2][4];
    #pragma unroll
    for (int nt = 0; nt < 4; ++nt) {
        const float b = eb2[nt * 16 + lc];
        c2[0][nt] = (f32x4){b, b, b, b};
        c2[1][nt] = (f32x4){b, b, b, b};
    }

    #pragma unroll 1
    for (int ch = 0; ch < NCH; ++ch) {
        #pragma unroll
        for (int t = 0; t < 2; ++t) {
            const int col = ch * 32 + t * 16 + lg * 4;   // acc cols (C-layout row = lg*4+r)
            u32x2 ya0 = *(const u32x2*)(Y + (size_t)d0 * H1P + col);
            u32x2 ya1 = *(const u32x2*)(Y + (size_t)d1 * H1P + col);
            f32x4 wl  = *(const f32x4*)(w1lf + col);
            f32x4 c10, c11;
            c10[0] = fmaf(rd0, wl[0], blo(ya0[0])); c10[1] = fmaf(rd0, wl[1], bhi(ya0[0]));
            c10[2] = fmaf(rd0, wl[2], blo(ya0[1])); c10[3] = fmaf(rd0, wl[3], bhi(ya0[1]));
            c11[0] = fmaf(rd1, wl[0], blo(ya1[0])); c11[1] = fmaf(rd1, wl[1], bhi(ya1[0]));
            c11[2] = fmaf(rd1, wl[2], blo(ya1[1])); c11[3] = fmaf(rd1, wl[3], bhi(ya1[1]));
            const int wrow = ch * 32 + t * 16 + lc;      // W1b row (A operand row = lc)
            #pragma unroll
            for (int kt = 0; kt < 4; ++kt) {
                bf16x8 AW = __builtin_bit_cast(bf16x8,
                    *(const u32x4*)(w1bh + (size_t)wrow * 256 + kt * 64 + lg * 16));
                c10 = mfma16(AW, BX[0][kt], c10);
                c11 = mfma16(AW, BX[1][kt], c11);
            }
            u32x2 v0, v1;
            v0[0] = pk2(silu(c10[0]), silu(c10[1])); v0[1] = pk2(silu(c10[2]), silu(c10[3]));
            v1[0] = pk2(silu(c11[0]), silu(c11[1])); v1[1] = pk2(silu(c11[2]), silu(c11[3]));
            *(u32x2*)(HT + lc * 80 + t * 32 + lg * 8) = v0;
            *(u32x2*)(HT + (16 + lc) * 80 + t * 32 + lg * 8) = v1;
        }
        LGKM0;
        bf16x8 A2[2];
        A2[0] = *(bf16x8*)(HT + lc * 80 + lg * 16);
        A2[1] = *(bf16x8*)(HT + (16 + lc) * 80 + lg * 16);
        LGKM0;   // A2 in regs before next chunk overwrites HT
        #pragma unroll
        for (int nt = 0; nt < 4; ++nt) {
            bf16x8 Bw = __builtin_bit_cast(bf16x8,
                *(const u32x4*)(w2b + (size_t)(nt * 16 + lc) * 1088 + ch * 64 + lg * 16));
            c2[0][nt] = mfma16(A2[0], Bw, c2[0][nt]);
            c2[1][nt] = mfma16(A2[1], Bw, c2[1][nt]);
        }
    }

    // ---- tail: silu -> m_ij into MJ; stream to gmij; coor MLP; gmh stream
    #pragma unroll
    for (int mt = 0; mt < 2; ++mt)
        #pragma unroll
        for (int nt = 0; nt < 4; ++nt)
            #pragma unroll
            for (int r = 0; r < 4; ++r) {
                const float v = silu(c2[mt][nt][r]);
                const int rowl = mt * 16 + lg * 4 + r;
                const int col  = nt * 16 + lc;
                *(u16*)(MJ + rowl * 136 + col * 2) = bfc(v);
            }
    LGKM0;

    {
        u16* grow = gmij + (size_t)ebase * 64;
        #pragma unroll
        for (int i = 0; i < 4; ++i) {
            const int row = i * 8 + (l >> 3);
            u32x4 v = *(u32x4*)(MJ + row * 136 + (l & 7) * 16);
            *(u32x4*)(grow + (size_t)row * 64 + (l & 7) * 8) = v;
        }
    }

    bf16x8 A3[2][2];
    #pragma unroll
    for (int mt = 0; mt < 2; ++mt)
        #pragma unroll
        for (int kt = 0; kt < 2; ++kt)
            A3[mt][kt] = *(bf16x8*)(MJ + (mt * 16 + lc) * 136 + kt * 64 + lg * 16);

    float pw[2][4] = {{0.f, 0.f, 0.f, 0.f}, {0.f, 0.f, 0.f, 0.f}};
    #pragma unroll 4
    for (int ct3 = 0; ct3 < 16; ++ct3) {
        const int col = ct3 * 16 + lc;
        const float b = cb1[col];
        f32x4 c30 = {b, b, b, b}, c31 = {b, b, b, b};
        #pragma unroll
        for (int kt = 0; kt < 2; ++kt) {
            bf16x8 B = __builtin_bit_cast(bf16x8,
                *(const u32x4*)(cw1b + (size_t)col * 128 + kt * 64 + lg * 16));
            c30 = mfma16(A3[0][kt], B, c30);
            c31 = mfma16(A3[1][kt], B, c31);
        }
        const float w2v = cw2[col];
        #pragma unroll
        for (int r = 0; r < 4; ++r) {
            pw[0][r] = fmaf(silu(c30[r]), w2v, pw[0][r]);
            pw[1][r] = fmaf(silu(c31[r]), w2v, pw[1][r]);
        }
    }
    #pragma unroll
    for (int m = 1; m < 16; m <<= 1)
        #pragma unroll
        for (int mt = 0; mt < 2; ++mt)
            #pragma unroll
            for (int r = 0; r < 4; ++r)
                pw[mt][r] += __shfl_xor(pw[mt][r], m, 64);

    const float cb2v = cb2[0];
    if (lc < 3) {
        #pragma unroll
        for (int mt = 0; mt < 2; ++mt)
            #pragma unroll
            for (int r = 0; r < 4; ++r) {
                const int rowl = mt * 16 + lg * 4 + r;
                const float cwv = pw[mt][r] + cb2v;
                gmh[(size_t)(ebase + rowl) * 4 + lc] = cwv * RDS[(w * 32 + rowl) * 4 + lc];
            }
    }
}

// ---------------- node kernel: LN + MLP via MFMA (passing since R7) ----------------

__global__ __launch_bounds__(256, 2) void node_mfma(
    const float* __restrict__ xc, const float* __restrict__ m_i, const float* __restrict__ mh,
    const float* __restrict__ ng, const float* __restrict__ nb,
    const char* __restrict__ nw1b, const float* __restrict__ nb1,
    const char* __restrict__ nw2b, const float* __restrict__ nb2,
    float* __restrict__ xn)
{
    __shared__ __align__(16) char LDS[4 * 4352];
    const int tid = threadIdx.x;
    const int w = tid >> 6, l = tid & 63, lg = l >> 4, lc = l & 15;
    char* HB = LDS + w * 4352;
    const int nb0 = blockIdx.x * 128 + w * 32;

    int nodes[2]; bool valid[2];
    #pragma unroll
    for (int et = 0; et < 2; ++et) {
        int n = nb0 + et * 16 + lc;
        valid[et] = (n < NN);
        nodes[et] = valid[et] ? n : (NN - 1);
    }

    bf16x8 BF[2][6];
    #pragma unroll
    for (int et = 0; et < 2; ++et) {
        const float* xr = xc + (size_t)nodes[et] * XD + 3;
        float v[4][8];
        float s = 0.f, q = 0.f;
        #pragma unroll
        for (int kt = 0; kt < 4; ++kt) {
            const int k0 = kt * 32 + lg * 8;
            #pragma unroll
            for (int j = 0; j < 8; ++j) {
                const float t = xr[k0 + j];
                v[kt][j] = t; s += t; q = fmaf(t, t, q);
            }
        }
        s += __shfl_xor(s, 16, 64); s += __shfl_xor(s, 32, 64);
        q += __shfl_xor(q, 16, 64); q += __shfl_xor(q, 32, 64);
        const float mu = s * (1.f / 128.f);
        const float rs = rsqrtf(q * (1.f / 128.f) - mu * mu + 1e-5f);
        #pragma unroll
        for (int kt = 0; kt < 4; ++kt) {
            const int k0 = kt * 32 + lg * 8;
            float4 g0 = *(const float4*)(ng + k0), g1 = *(const float4*)(ng + k0 + 4);
            float4 b0 = *(const float4*)(nb + k0), b1 = *(const float4*)(nb + k0 + 4);
            const u32 u0 = pk2((v[kt][0] - mu) * rs * g0.x + b0.x, (v[kt][1] - mu) * rs * g0.y + b0.y);
            const u32 u1 = pk2((v[kt][2] - mu) * rs * g0.z + b0.z, (v[kt][3] - mu) * rs * g0.w + b0.w);
            const u32 u2 = pk2((v[kt][4] - mu) * rs * g1.x + b1.x, (v[kt][5] - mu) * rs * g1.y + b1.y);
            const u32 u3 = pk2((v[kt][6] - mu) * rs * g1.z + b1.z, (v[kt][7] - mu) * rs * g1.w + b1.w);
            BF[et][kt] = mk8(u0, u1, u2, u3);
        }
        const float* mr = m_i + (size_t)nodes[et] * 64;
        #pragma unroll
        for (int kt2 = 0; kt2 < 2; ++kt2) {
            float4 a = *(const float4*)(mr + kt2 * 32 + lg * 8);
            float4 b = *(const float4*)(mr + kt2 * 32 + lg * 8 + 4);
            BF[et][4 + kt2] = mk8(pk2(a.x, a.y), pk2(a.z, a.w), pk2(b.x, b.y), pk2(b.z, b.w));
        }
    }

    f32x4 a2[8][2];
    #pragma unroll
    for (int ct2 = 0; ct2 < 8; ++ct2) {
        f32x4 b = *(const f32x4*)(nb2 + ct2 * 16 + lg * 4);
        a2[ct2][0] = b; a2[ct2][1] = b;
    }

    #pragma unroll 1
    for (int g = 0; g < 4; ++g) {
        f32x4 a1[4][2];
        #pragma unroll
        for (int ct = 0; ct < 4; ++ct) {
            f32x4 b = *(const f32x4*)(nb1 + g * 64 + ct * 16 + lg * 4);
            a1[ct][0] = b; a1[ct][1] = b;
        }
        #pragma unroll
        for (int ct = 0; ct < 4; ++ct)
            #pragma unroll
            for (int kt = 0; kt < 6; ++kt) {
                bf16x8 Aw = __builtin_bit_cast(bf16x8, *(const u32x4*)(
                    nw1b + (size_t)(g * 64 + ct * 16 + lc) * 384 + kt * 64 + lg * 16));
                a1[ct][0] = mfma16(Aw, BF[0][kt], a1[ct][0]);
                a1[ct][1] = mfma16(Aw, BF[1][kt], a1[ct][1]);
            }
        #pragma unroll
        for (int ct = 0; ct < 4; ++ct)
            #pragma unroll
            for (int et = 0; et < 2; ++et) {
                f32x4 c = a1[ct][et];
                u32 v0 = pk2(silu(c[0]), silu(c[1]));
                u32 v1 = pk2(silu(c[2]), silu(c[3]));
                *(u32*)(HB + (et * 16 + lc) * 136 + ct * 32 + lg * 8) = v0;
                *(u32*)(HB + (et * 16 + lc) * 136 + ct * 32 + lg * 8 + 4) = v1;
            }
        LGKM0;
        __builtin_amdgcn_sched_barrier(0);
        bf16x8 B2[2][2];
        #pragma unroll
        for (int et = 0; et < 2; ++et)
            #pragma unroll
            for (int kt2 = 0; kt2 < 2; ++kt2) {
                u32 a = *(u32*)(HB + (et * 16 + lc) * 136 + kt2 * 64 + lg * 16);
                u32 b = *(u32*)(HB + (et * 16 + lc) * 136 + kt2 * 64 + lg * 16 + 4);
                u32 c = *(u32*)(HB + (et * 16 + lc) * 136 + kt2 * 64 + lg * 16 + 8);
                u32 d = *(u32*)(HB + (et * 16 + lc) * 136 + kt2 * 64 + lg * 16 + 12);
                B2[et][kt2] = mk8(a, b, c, d);
            }
        #pragma unroll
        for (int ct2 = 0; ct2 < 8; ++ct2)
            #pragma unroll
            for (int kt2 = 0; kt2 < 2; ++kt2) {
                bf16x8 Aw = __builtin_bit_cast(bf16x8, *(const u32x4*)(
                    nw2b + (size_t)(ct2 * 16 + lc) * 512 + (g * 64 + kt2 * 32 + lg * 8) * 2));
                a2[ct2][0] = mfma16(Aw, B2[0][kt2], a2[ct2][0]);
                a2[ct2][1] = mfma16(Aw, B2[1][kt2], a2[ct2][1]);
            }
        LGKM0;
        __builtin_amdgcn_sched_barrier(0);
    }

    #pragma unroll
    for (int et = 0; et < 2; ++et) {
        if (!valid[et]) continue;
        const size_t nr = (size_t)nodes[et] * XD;
        #pragma unroll
        for (int ct2 = 0; ct2 < 8; ++ct2)
            #pragma unroll
            for (int r = 0; r < 4; ++r) {
                const int col = ct2 * 16 + lg * 4 + r;
                xn[nr + 3 + col] = a2[ct2][et][r] + xc[nr + 3 + col];
            }
    }
    for (int idx = tid; idx < 384; idx += 256) {
        const int n = blockIdx.x * 128 + idx / 3;
        const int d = idx - (idx / 3) * 3;
        if (n < NN)
            xn[(size_t)n * XD + d] = xc[(size_t)n * XD + d] + mh[n * 3 + d];
    }
}

// ---------------- launch ----------------

extern "C" void kernel_launch(void* const* d_in, const int* in_sizes, int n_in,
                              void* d_out, int out_size, void* d_ws, size_t ws_size,
                              hipStream_t stream) {
    const float* x_in = (const float*)d_in[0];
    const int*   eidx = (const int*)  d_in[1];
    const float* ew1  = (const float*)d_in[2];
    const float* eb1  = (const float*)d_in[3];
    const float* ew2  = (const float*)d_in[4];
    const float* eb2  = (const float*)d_in[5];
    const float* ng   = (const float*)d_in[6];
    const float* nb   = (const float*)d_in[7];
    const float* nw1  = (const float*)d_in[8];
    const float* nb1  = (const float*)d_in[9];
    const float* nw2  = (const float*)d_in[10];
    const float* nb2  = (const float*)d_in[11];
    const float* cw1  = (const float*)d_in[12];
    const float* cb1  = (const float*)d_in[13];
    const float* cw2  = (const float*)d_in[14];
    const float* cb2  = (const float*)d_in[15];
    float* out = (float*)d_out;

    char* ws = (char*)d_ws;
    size_t off = 0;
    auto alloc = [&](size_t bytes) { char* p = ws + off; off = (off + bytes + 255) & ~255ull; return p; };
    float* mi    = (float*)alloc((size_t)NN * MD * 4);
    float* mh    = (float*)alloc((size_t)NN * 3 * 4);
    u32*   xbf   = (u32*)  alloc((size_t)NN * 256);
    float* eb1pf = (float*)alloc((size_t)3 * H1P * 4);
    float* w1lf  = (float*)alloc((size_t)3 * H1P * 4);
    char*  w1p   = alloc((size_t)3 * 1088 * 256);
    char*  w2b   = alloc((size_t)3 * 64 * 1088);
    char*  cw1b  = alloc((size_t)3 * 256 * 128);
    char*  nw1b  = alloc((size_t)3 * 256 * 384);
    char*  nw2b  = alloc((size_t)3 * 128 * 512);
    int* rowp = (int*) alloc((size_t)(NN + 1) * 4);
    int* eids = (int*) alloc((size_t)NE * 4);
    int* esrc = (int*) alloc((size_t)NE * 4);
    int* edst = (int*) alloc((size_t)NE * 4);
    int* cnt  = (int*) alloc((size_t)NN * 4);
    int* fillp= (int*) alloc((size_t)NN * 4);
    u16* gmij = (u16*)alloc((size_t)NE * 64 * 2);      // 41 MB
    float* gmh= (float*)alloc((size_t)NE * 4 * 4);     // 5.1 MB
    u16* Ybuf = (u16*)alloc((size_t)NN * H1P * 2);     // 21.8 MB  (total ~85 MB, proven fits)

    prep_w1n<<<(3 * 1088 * 128 + 255) / 256, 256, 0, stream>>>(ew1, eb1, (u16*)w1p, eb1pf, w1lf);
    prep_w2 <<<(3 * 64 * H1P + 255) / 256, 256, 0, stream>>>(ew2, (u16*)w2b);
    prep_cw1<<<(3 * 256 * 64 + 255) / 256, 256, 0, stream>>>(cw1, (u16*)cw1b);
    prep_nw1<<<(3 * 256 * 192 + 255) / 256, 256, 0, stream>>>(nw1, (u16*)nw1b);
    prep_nw2<<<(3 * 128 * 256 + 255) / 256, 256, 0, stream>>>(nw2, (u16*)nw2b);

    hipMemsetAsync(cnt,  0, (size_t)NN * 4, stream);
    hipMemsetAsync(fillp,0, (size_t)NN * 4, stream);
    csr_hist<<<(NE + 255) / 256, 256, 0, stream>>>(eidx, cnt);
    csr_scan<<<1, 1024, 0, stream>>>(cnt, rowp);
    csr_fill<<<(NE + 255) / 256, 256, 0, stream>>>(eidx, rowp, fillp, eids);
    esort<<<(NE + 255) / 256, 256, 0, stream>>>(eidx, eids, esrc, edst);

    for (int l = 0; l < 3; ++l) {
        const float* xc = (l == 0) ? x_in : out;
        float*       xn = out;
        x2bf<<<(NN * 64 + 255) / 256, 256, 0, stream>>>(xc, xbf);
        ygemm<<<dim3((NN + 127) / 128, 2), 256, 0, stream>>>(
            (const u16*)xbf, w1p + (size_t)l * 1088 * 256, eb1pf + (size_t)l * H1P, Ybuf);
        edge_mfma3<<<NE / 128, 256, 0, stream>>>(
            xc, Ybuf, (const u16*)xbf, esrc, edst,
            w1p + ((size_t)l * 1088 + H1P) * 256, w1lf + (size_t)l * H1P,
            w2b + (size_t)l * 64 * 1088, eb2 + (size_t)l * 64,
            cw1b + (size_t)l * 256 * 128, cb1 + (size_t)l * 256,
            cw2 + (size_t)l * 256, cb2 + l, gmij, gmh);
        reduce_mi<<<(NN + 7) / 8, 256, 0, stream>>>(gmij, gmh, rowp, mi, mh);
        node_mfma<<<(NN + 127) / 128, 256, 0, stream>>>(
            xc, mi, mh,
            ng + (size_t)l * F, nb + (size_t)l * F,
            nw1b + (size_t)l * 256 * 384, nb1 + (size_t)l * 256,
            nw2b + (size_t)l * 128 * 512, nb2 + (size_t)l * F,
            xn);
    }
}

// Round 15
// 820.357 us; speedup vs baseline: 1.6108x; 1.6108x over previous
//
#include <hip/hip_runtime.h>

typedef unsigned short u16;
typedef unsigned int   u32;
typedef __attribute__((ext_vector_type(2))) u32  u32x2;
typedef __attribute__((ext_vector_type(4))) u32  u32x4;
typedef __attribute__((ext_vector_type(8))) __bf16 bf16x8;
typedef __attribute__((ext_vector_type(4))) float  f32x4;

#define NN 20000
#define NE 320000
#define XD 131
#define F  128
#define MD 64
#define H1 514
#define H1P 544
#define NCH 17

#define GAS __attribute__((address_space(1)))
#define LAS __attribute__((address_space(3)))
#define LGKM0 asm volatile("s_waitcnt lgkmcnt(0)" ::: "memory")

__device__ __forceinline__ float silu(float a) {
    float e = __expf(-a);
    return a * __builtin_amdgcn_rcpf(1.0f + e);
}

__device__ __forceinline__ u16 f2bf(float f) {   // fp32 -> bf16 RNE
    u32 u = __builtin_bit_cast(u32, f);
    return (u16)((u + 0x7FFFu + ((u >> 16) & 1u)) >> 16);
}
__device__ __forceinline__ u16 bfc(float f) { return __builtin_bit_cast(u16, (__bf16)f); }
__device__ __forceinline__ u32 pk2(float a, float b) {
    return (u32)bfc(a) | ((u32)bfc(b) << 16);
}
__device__ __forceinline__ float blo(u32 u) { return __builtin_bit_cast(float, u << 16); }
__device__ __forceinline__ float bhi(u32 u) { return __builtin_bit_cast(float, u & 0xFFFF0000u); }
__device__ __forceinline__ bf16x8 mk8(u32 a, u32 b, u32 c, u32 d) {
    u32x4 t = {a, b, c, d};
    return __builtin_bit_cast(bf16x8, t);
}
__device__ __forceinline__ f32x4 mfma16(bf16x8 a, bf16x8 b, f32x4 c) {
    return __builtin_amdgcn_mfma_f32_16x16x32_bf16(a, b, c, 0, 0, 0);
}

// ---------------- weight prep ----------------

// w1p[l][n<1088][k<128] 256B rows. n<544: Ya cols (W1 rows 0..127); n>=544: Yb cols (rows 128..255).
__global__ void prep_w1n(const float* __restrict__ ew1, const float* __restrict__ eb1,
                         u16* __restrict__ w1p, float* __restrict__ eb1p, float* __restrict__ w1lf) {
    int i = blockIdx.x * 256 + threadIdx.x;
    if (i >= 3 * 1088 * 128) return;
    int k = i & 127;
    int n = (i >> 7) % 1088;
    int l = (i >> 7) / 1088;
    float v;
    if (n < H1P) v = (n < H1) ? ew1[(size_t)l * 257 * H1 + (size_t)k * H1 + n] : 0.f;
    else { int nn = n - H1P; v = (nn < H1) ? ew1[(size_t)l * 257 * H1 + (size_t)(128 + k) * H1 + nn] : 0.f; }
    w1p[(size_t)(l * 1088 + n) * 128 + k] = f2bf(v);
    if (k == 0 && n < H1P) {
        eb1p[l * H1P + n] = (n < H1) ? eb1[l * H1 + n] : 0.f;
        w1lf[l * H1P + n] = (n < H1) ? ew1[(size_t)l * 257 * H1 + (size_t)256 * H1 + n] : 0.f;
    }
}

__global__ void prep_w2(const float* __restrict__ ew2, u16* __restrict__ w2b) {
    int i = blockIdx.x * 256 + threadIdx.x;
    if (i >= 3 * 64 * H1P) return;
    int k = i % H1P;
    int n = (i / H1P) & 63;
    int l = i / (H1P * 64);
    float v = (k < H1) ? ew2[(size_t)l * H1 * 64 + (size_t)k * 64 + n] : 0.f;
    w2b[(size_t)(l * 64 + n) * H1P + k] = f2bf(v);
}

__global__ void prep_cw1(const float* __restrict__ cw1, u16* __restrict__ cw1b) {
    int i = blockIdx.x * 256 + threadIdx.x;
    if (i >= 3 * 256 * 64) return;
    int k = i & 63;
    int n = (i >> 6) & 255;
    int l = i >> 14;
    cw1b[(size_t)l * 16384 + n * 64 + k] = f2bf(cw1[(size_t)l * 16384 + k * 256 + n]);
}

__global__ void prep_nw1(const float* __restrict__ nw1, u16* __restrict__ nw1b) {
    int i = blockIdx.x * 256 + threadIdx.x;
    if (i >= 3 * 256 * 192) return;
    int k = i % 192;
    int n = (i / 192) & 255;
    int l = i / (192 * 256);
    nw1b[(size_t)(l * 256 + n) * 192 + k] = f2bf(nw1[(size_t)l * 192 * 256 + (size_t)k * 256 + n]);
}

__global__ void prep_nw2(const float* __restrict__ nw2, u16* __restrict__ nw2b) {
    int i = blockIdx.x * 256 + threadIdx.x;
    if (i >= 3 * 128 * 256) return;
    int k = i & 255;
    int n = (i >> 8) & 127;
    int l = i >> 15;
    nw2b[(size_t)(l * 128 + n) * 256 + k] = f2bf(nw2[(size_t)l * 256 * 128 + (size_t)k * 128 + n]);
}

// ---------------- Y precompute: Y[v][0:544]=X@W1a+b, Y[v][544:1088]=X@W1b ----------------
// grid (157, 4): x = node-tile (128 nodes, 4 waves x 32), y = col-group (17 tiles of 16).
// Reads x fp32 directly (inline bf16 conversion) — x2bf pass eliminated.

__global__ __launch_bounds__(256, 4) void ygemm(
    const float* __restrict__ xc, const char* __restrict__ w1p,
    const float* __restrict__ eb1p, u16* __restrict__ Y)
{
    const int tid = threadIdx.x;
    const int w = tid >> 6, l = tid & 63, lg = l >> 4, lc = l & 15;
    const int nb0 = blockIdx.x * 128 + w * 32;
    const int n0 = nb0 + lc, n1 = nb0 + 16 + lc;
    const bool v0 = n0 < NN, v1 = n1 < NN;
    const int m0 = v0 ? n0 : NN - 1, m1 = v1 ? n1 : NN - 1;

    bf16x8 BF[2][4];
    #pragma unroll
    for (int et = 0; et < 2; ++et) {
        const float* xr = xc + (size_t)(et ? m1 : m0) * XD + 3;
        #pragma unroll
        for (int kt = 0; kt < 4; ++kt) {
            const int k0 = kt * 32 + lg * 8;
            float4 a = *(const float4*)(xr + k0);
            float4 b = *(const float4*)(xr + k0 + 4);
            BF[et][kt] = mk8(pk2(a.x, a.y), pk2(a.z, a.w), pk2(b.x, b.y), pk2(b.z, b.w));
        }
    }

    const int t0 = blockIdx.y * 17;
    #pragma unroll 1
    for (int t = t0; t < t0 + 17; ++t) {
        bf16x8 AW[4];
        #pragma unroll
        for (int kt = 0; kt < 4; ++kt)
            AW[kt] = *(const bf16x8*)(w1p + (size_t)(t * 16 + lc) * 256 + kt * 64 + lg * 16);
        const int cb = t * 16 + lg * 4;            // output cols cb..cb+3
        f32x4 binit = {0.f, 0.f, 0.f, 0.f};
        if (cb < H1P) binit = *(const f32x4*)(eb1p + cb);   // bias folded into Ya half
        f32x4 c0 = binit, c1 = binit;
        #pragma unroll
        for (int kt = 0; kt < 4; ++kt) {
            c0 = mfma16(AW[kt], BF[0][kt], c0);    // D[m=col][n=node]
            c1 = mfma16(AW[kt], BF[1][kt], c1);
        }
        u32x2 p0, p1;
        p0[0] = pk2(c0[0], c0[1]); p0[1] = pk2(c0[2], c0[3]);
        p1[0] = pk2(c1[0], c1[1]); p1[1] = pk2(c1[2], c1[3]);
        if (v0) *(u32x2*)(Y + (size_t)m0 * 1088 + cb) = p0;
        if (v1) *(u32x2*)(Y + (size_t)m1 * 1088 + cb) = p1;
    }
}

// ---------------- CSR build + edge sort (once per launch; graph constant) ----------------

__global__ void csr_hist(const int* __restrict__ eidx, int* __restrict__ cnt) {
    int e = blockIdx.x * 256 + threadIdx.x;
    if (e < NE) atomicAdd(&cnt[eidx[NE + e]], 1);
}

__global__ void csr_scan(const int* __restrict__ cnt, int* __restrict__ rowp) {
    __shared__ int ps[1024];
    const int t = threadIdx.x;
    const int base = t * 20;
    int loc[20];
    int s = 0;
    #pragma unroll
    for (int i = 0; i < 20; ++i) {
        const int idx = base + i;
        const int c = (idx < NN) ? cnt[idx] : 0;
        loc[i] = s;
        s += c;
    }
    ps[t] = s;
    __syncthreads();
    for (int off = 1; off < 1024; off <<= 1) {
        int v = (t >= off) ? ps[t - off] : 0;
        __syncthreads();
        ps[t] += v;
        __syncthreads();
    }
    const int segbase = (t > 0) ? ps[t - 1] : 0;
    #pragma unroll
    for (int i = 0; i < 20; ++i) {
        const int idx = base + i;
        if (idx < NN) rowp[idx] = segbase + loc[i];
    }
    if (t == 1023) rowp[NN] = ps[1023];
}

__global__ void csr_fill(const int* __restrict__ eidx, const int* __restrict__ rowp,
                         int* __restrict__ fill, int* __restrict__ eids) {
    int e = blockIdx.x * 256 + threadIdx.x;
    if (e >= NE) return;
    const int d = eidx[NE + e];
    const int pos = atomicAdd(&fill[d], 1);
    eids[rowp[d] + pos] = e;
}

__global__ void esort(const int* __restrict__ eidx, const int* __restrict__ eids,
                      int* __restrict__ esrc, int* __restrict__ edst) {
    int j = blockIdx.x * 256 + threadIdx.x;
    if (j >= NE) return;
    const int e = eids[j];
    esrc[j] = eidx[e];
    edst[j] = eidx[NE + e];
}

// ---------------- segment sums over contiguous sorted rows ----------------

__global__ __launch_bounds__(256, 4) void reduce_mi(
    const u16* __restrict__ gmij, const float* __restrict__ gmh,
    const int* __restrict__ rowp, float* __restrict__ m_i, float* __restrict__ mh) {
    const int tid = threadIdx.x;
    const int n = blockIdx.x * 8 + (tid >> 5);
    const int t = tid & 31;
    if (n >= NN) return;
    const int b = rowp[n], e = rowp[n + 1];
    float a0 = 0.f, a1 = 0.f;
    for (int j = b; j < e; ++j) {
        const u32 v = *(const u32*)(gmij + (size_t)j * 64 + t * 2);
        a0 += blo(v);
        a1 += bhi(v);
    }
    m_i[(size_t)n * 64 + 2 * t]     = a0;
    m_i[(size_t)n * 64 + 2 * t + 1] = a1;
    if (t < 3) {
        float m = 0.f;
        for (int j = b; j < e; ++j) m += gmh[(size_t)j * 4 + t];
        mh[n * 3 + t] = m;
    }
}

// ---------------- edge kernel (R12 structure, LB 4->6 for latency hiding) ----------------
// 128 edges/block, 4 waves x 32 edges. h = silu(Ya[dst] + Yb[src] + rd*wl) elementwise;
// MLP2/coor via MFMA. Barrier-free (wave-private LDS + LGKM waits only).

__global__ __launch_bounds__(256, 6) void edge_mfma2(
    const float* __restrict__ x, const u16* __restrict__ Y,
    const int* __restrict__ esrc, const int* __restrict__ edst,
    const float* __restrict__ w1lf,
    const char* __restrict__ w2b, const float* __restrict__ eb2,
    const char* __restrict__ cw1b, const float* __restrict__ cb1,
    const float* __restrict__ cw2, const float* __restrict__ cb2,
    u16* __restrict__ gmij, float* __restrict__ gmh)
{
    __shared__ __align__(16) char LDS[19456];   // [0,17408) MJ per-wave 4352B; [17408,19456) RDS
    const int tid = threadIdx.x;
    const int w = tid >> 6, l = tid & 63, lg = l >> 4, lc = l & 15;
    const int ebase = blockIdx.x * 128 + w * 32;
    char*  MJ  = LDS + w * 4352;
    float* RDS = (float*)(LDS + 17408);

    // per-edge geometry (lanes l<32, wave-private rows; LGKM-only sync)
    if (l < 32) {
        const int e = ebase + l;
        const int s = esrc[e], d = edst[e];
        const float ax = x[(size_t)s * XD + 0] - x[(size_t)d * XD + 0];
        const float ay = x[(size_t)s * XD + 1] - x[(size_t)d * XD + 1];
        const float az = x[(size_t)s * XD + 2] - x[(size_t)d * XD + 2];
        f32x4 v = {ax, ay, az, ax * ax + ay * ay + az * az};
        *(f32x4*)(RDS + (w * 32 + l) * 4) = v;
    }
    const int s0 = esrc[ebase + lc],      d0 = edst[ebase + lc];
    const int s1 = esrc[ebase + 16 + lc], d1 = edst[ebase + 16 + lc];
    LGKM0;
    const float rd0 = RDS[(w * 32 + lc) * 4 + 3];
    const float rd1 = RDS[(w * 32 + 16 + lc) * 4 + 3];

    f32x4 c2[2][4];
    #pragma unroll
    for (int nt = 0; nt < 4; ++nt) {
        const float b = eb2[nt * 16 + lc];
        c2[0][nt] = (f32x4){b, b, b, b};
        c2[1][nt] = (f32x4){b, b, b, b};
    }

    #pragma unroll 1
    for (int ch = 0; ch < NCH; ++ch) {
        const int cb = ch * 32 + lg * 8;
        u32x4 ya0 = *(const u32x4*)(Y + (size_t)d0 * 1088 + cb);
        u32x4 yb0 = *(const u32x4*)(Y + (size_t)s0 * 1088 + 544 + cb);
        u32x4 ya1 = *(const u32x4*)(Y + (size_t)d1 * 1088 + cb);
        u32x4 yb1 = *(const u32x4*)(Y + (size_t)s1 * 1088 + 544 + cb);
        f32x4 wlA = *(const f32x4*)(w1lf + cb);
        f32x4 wlB = *(const f32x4*)(w1lf + cb + 4);
        u32 pk0[4], pk1[4];
        #pragma unroll
        for (int j = 0; j < 4; ++j) {
            const float wa = (j < 2) ? wlA[2 * j]     : wlB[2 * j - 4];
            const float wb = (j < 2) ? wlA[2 * j + 1] : wlB[2 * j - 3];
            {
                const float a0 = blo(ya0[j]) + blo(yb0[j]) + rd0 * wa;
                const float a1 = bhi(ya0[j]) + bhi(yb0[j]) + rd0 * wb;
                pk0[j] = pk2(silu(a0), silu(a1));
            }
            {
                const float a0 = blo(ya1[j]) + blo(yb1[j]) + rd1 * wa;
                const float a1 = bhi(ya1[j]) + bhi(yb1[j]) + rd1 * wb;
                pk1[j] = pk2(silu(a0), silu(a1));
            }
        }
        bf16x8 A20 = mk8(pk0[0], pk0[1], pk0[2], pk0[3]);
        bf16x8 A21 = mk8(pk1[0], pk1[1], pk1[2], pk1[3]);
        #pragma unroll
        for (int nt = 0; nt < 4; ++nt) {
            bf16x8 Bw = __builtin_bit_cast(bf16x8,
                *(const u32x4*)(w2b + (size_t)(nt * 16 + lc) * 1088 + ch * 64 + lg * 16));
            c2[0][nt] = mfma16(A20, Bw, c2[0][nt]);
            c2[1][nt] = mfma16(A21, Bw, c2[1][nt]);
        }
    }

    // ---- tail: silu -> m_ij into MJ; stream to gmij; coor MLP; gmh stream
    #pragma unroll
    for (int mt = 0; mt < 2; ++mt)
        #pragma unroll
        for (int nt = 0; nt < 4; ++nt)
            #pragma unroll
            for (int r = 0; r < 4; ++r) {
                const float v = silu(c2[mt][nt][r]);
                const int rowl = mt * 16 + lg * 4 + r;
                const int col  = nt * 16 + lc;
                *(u16*)(MJ + rowl * 136 + col * 2) = bfc(v);
            }
    LGKM0;

    {
        u16* grow = gmij + (size_t)ebase * 64;
        #pragma unroll
        for (int i = 0; i < 4; ++i) {
            const int row = i * 8 + (l >> 3);
            u32x4 v = *(u32x4*)(MJ + row * 136 + (l & 7) * 16);
            *(u32x4*)(grow + (size_t)row * 64 + (l & 7) * 8) = v;
        }
    }

    bf16x8 A3[2][2];
    #pragma unroll
    for (int mt = 0; mt < 2; ++mt)
        #pragma unroll
        for (int kt = 0; kt < 2; ++kt)
            A3[mt][kt] = *(bf16x8*)(MJ + (mt * 16 + lc) * 136 + kt * 64 + lg * 16);

    float pw[2][4] = {{0.f, 0.f, 0.f, 0.f}, {0.f, 0.f, 0.f, 0.f}};
    #pragma unroll 4
    for (int ct3 = 0; ct3 < 16; ++ct3) {
        const int col = ct3 * 16 + lc;
        const float b = cb1[col];
        f32x4 c30 = {b, b, b, b}, c31 = {b, b, b, b};
        #pragma unroll
        for (int kt = 0; kt < 2; ++kt) {
            bf16x8 B = __builtin_bit_cast(bf16x8,
                *(const u32x4*)(cw1b + (size_t)col * 128 + kt * 64 + lg * 16));
            c30 = mfma16(A3[0][kt], B, c30);
            c31 = mfma16(A3[1][kt], B, c31);
        }
        const float w2v = cw2[col];
        #pragma unroll
        for (int r = 0; r < 4; ++r) {
            pw[0][r] = fmaf(silu(c30[r]), w2v, pw[0][r]);
            pw[1][r] = fmaf(silu(c31[r]), w2v, pw[1][r]);
        }
    }
    #pragma unroll
    for (int m = 1; m < 16; m <<= 1)
        #pragma unroll
        for (int mt = 0; mt < 2; ++mt)
            #pragma unroll
            for (int r = 0; r < 4; ++r)
                pw[mt][r] += __shfl_xor(pw[mt][r], m, 64);

    const float cb2v = cb2[0];
    if (lc < 3) {
        #pragma unroll
        for (int mt = 0; mt < 2; ++mt)
            #pragma unroll
            for (int r = 0; r < 4; ++r) {
                const int rowl = mt * 16 + lg * 4 + r;
                const float cwv = pw[mt][r] + cb2v;
                gmh[(size_t)(ebase + rowl) * 4 + lc] = cwv * RDS[(w * 32 + rowl) * 4 + lc];
            }
    }
}

// ---------------- node kernel: LN + MLP via MFMA (passing since R7) ----------------

__global__ __launch_bounds__(256, 2) void node_mfma(
    const float* __restrict__ xc, const float* __restrict__ m_i, const float* __restrict__ mh,
    const float* __restrict__ ng, const float* __restrict__ nb,
    const char* __restrict__ nw1b, const float* __restrict__ nb1,
    const char* __restrict__ nw2b, const float* __restrict__ nb2,
    float* __restrict__ xn)
{
    __shared__ __align__(16) char LDS[4 * 4352];
    const int tid = threadIdx.x;
    const int w = tid >> 6, l = tid & 63, lg = l >> 4, lc = l & 15;
    char* HB = LDS + w * 4352;
    const int nb0 = blockIdx.x * 128 + w * 32;

    int nodes[2]; bool valid[2];
    #pragma unroll
    for (int et = 0; et < 2; ++et) {
        int n = nb0 + et * 16 + lc;
        valid[et] = (n < NN);
        nodes[et] = valid[et] ? n : (NN - 1);
    }

    bf16x8 BF[2][6];
    #pragma unroll
    for (int et = 0; et < 2; ++et) {
        const float* xr = xc + (size_t)nodes[et] * XD + 3;
        float v[4][8];
        float s = 0.f, q = 0.f;
        #pragma unroll
        for (int kt = 0; kt < 4; ++kt) {
            const int k0 = kt * 32 + lg * 8;
            #pragma unroll
            for (int j = 0; j < 8; ++j) {
                const float t = xr[k0 + j];
                v[kt][j] = t; s += t; q = fmaf(t, t, q);
            }
        }
        s += __shfl_xor(s, 16, 64); s += __shfl_xor(s, 32, 64);
        q += __shfl_xor(q, 16, 64); q += __shfl_xor(q, 32, 64);
        const float mu = s * (1.f / 128.f);
        const float rs = rsqrtf(q * (1.f / 128.f) - mu * mu + 1e-5f);
        #pragma unroll
        for (int kt = 0; kt < 4; ++kt) {
            const int k0 = kt * 32 + lg * 8;
            float4 g0 = *(const float4*)(ng + k0), g1 = *(const float4*)(ng + k0 + 4);
            float4 b0 = *(const float4*)(nb + k0), b1 = *(const float4*)(nb + k0 + 4);
            const u32 u0 = pk2((v[kt][0] - mu) * rs * g0.x + b0.x, (v[kt][1] - mu) * rs * g0.y + b0.y);
            const u32 u1 = pk2((v[kt][2] - mu) * rs * g0.z + b0.z, (v[kt][3] - mu) * rs * g0.w + b0.w);
            const u32 u2 = pk2((v[kt][4] - mu) * rs * g1.x + b1.x, (v[kt][5] - mu) * rs * g1.y + b1.y);
            const u32 u3 = pk2((v[kt][6] - mu) * rs * g1.z + b1.z, (v[kt][7] - mu) * rs * g1.w + b1.w);
            BF[et][kt] = mk8(u0, u1, u2, u3);
        }
        const float* mr = m_i + (size_t)nodes[et] * 64;
        #pragma unroll
        for (int kt2 = 0; kt2 < 2; ++kt2) {
            float4 a = *(const float4*)(mr + kt2 * 32 + lg * 8);
            float4 b = *(const float4*)(mr + kt2 * 32 + lg * 8 + 4);
            BF[et][4 + kt2] = mk8(pk2(a.x, a.y), pk2(a.z, a.w), pk2(b.x, b.y), pk2(b.z, b.w));
        }
    }

    f32x4 a2[8][2];
    #pragma unroll
    for (int ct2 = 0; ct2 < 8; ++ct2) {
        f32x4 b = *(const f32x4*)(nb2 + ct2 * 16 + lg * 4);
        a2[ct2][0] = b; a2[ct2][1] = b;
    }

    #pragma unroll 1
    for (int g = 0; g < 4; ++g) {
        f32x4 a1[4][2];
        #pragma unroll
        for (int ct = 0; ct < 4; ++ct) {
            f32x4 b = *(const f32x4*)(nb1 + g * 64 + ct * 16 + lg * 4);
            a1[ct][0] = b; a1[ct][1] = b;
        }
        #pragma unroll
        for (int ct = 0; ct < 4; ++ct)
            #pragma unroll
            for (int kt = 0; kt < 6; ++kt) {
                bf16x8 Aw = __builtin_bit_cast(bf16x8, *(const u32x4*)(
                    nw1b + (size_t)(g * 64 + ct * 16 + lc) * 384 + kt * 64 + lg * 16));
                a1[ct][0] = mfma16(Aw, BF[0][kt], a1[ct][0]);
                a1[ct][1] = mfma16(Aw, BF[1][kt], a1[ct][1]);
            }
        #pragma unroll
        for (int ct = 0; ct < 4; ++ct)
            #pragma unroll
            for (int et = 0; et < 2; ++et) {
                f32x4 c = a1[ct][et];
                u32 v0 = pk2(silu(c[0]), silu(c[1]));
                u32 v1 = pk2(silu(c[2]), silu(c[3]));
                *(u32*)(HB + (et * 16 + lc) * 136 + ct * 32 + lg * 8) = v0;
                *(u32*)(HB + (et * 16 + lc) * 136 + ct * 32 + lg * 8 + 4) = v1;
            }
        LGKM0;
        __builtin_amdgcn_sched_barrier(0);
        bf16x8 B2[2][2];
        #pragma unroll
        for (int et = 0; et < 2; ++et)
            #pragma unroll
            for (int kt2 = 0; kt2 < 2; ++kt2) {
                u32 a = *(u32*)(HB + (et * 16 + lc) * 136 + kt2 * 64 + lg * 16);
                u32 b = *(u32*)(HB + (et * 16 + lc) * 136 + kt2 * 64 + lg * 16 + 4);
                u32 c = *(u32*)(HB + (et * 16 + lc) * 136 + kt2 * 64 + lg * 16 + 8);
                u32 d = *(u32*)(HB + (et * 16 + lc) * 136 + kt2 * 64 + lg * 16 + 12);
                B2[et][kt2] = mk8(a, b, c, d);
            }
        #pragma unroll
        for (int ct2 = 0; ct2 < 8; ++ct2)
            #pragma unroll
            for (int kt2 = 0; kt2 < 2; ++kt2) {
                bf16x8 Aw = __builtin_bit_cast(bf16x8, *(const u32x4*)(
                    nw2b + (size_t)(ct2 * 16 + lc) * 512 + (g * 64 + kt2 * 32 + lg * 8) * 2));
                a2[ct2][0] = mfma16(Aw, B2[0][kt2], a2[ct2][0]);
                a2[ct2][1] = mfma16(Aw, B2[1][kt2], a2[ct2][1]);
            }
        LGKM0;
        __builtin_amdgcn_sched_barrier(0);
    }

    #pragma unroll
    for (int et = 0; et < 2; ++et) {
        if (!valid[et]) continue;
        const size_t nr = (size_t)nodes[et] * XD;
        #pragma unroll
        for (int ct2 = 0; ct2 < 8; ++ct2)
            #pragma unroll
            for (int r = 0; r < 4; ++r) {
                const int col = ct2 * 16 + lg * 4 + r;
                xn[nr + 3 + col] = a2[ct2][et][r] + xc[nr + 3 + col];
            }
    }
    for (int idx = tid; idx < 384; idx += 256) {
        const int n = blockIdx.x * 128 + idx / 3;
        const int d = idx - (idx / 3) * 3;
        if (n < NN)
            xn[(size_t)n * XD + d] = xc[(size_t)n * XD + d] + mh[n * 3 + d];
    }
}

// ---------------- launch ----------------

extern "C" void kernel_launch(void* const* d_in, const int* in_sizes, int n_in,
                              void* d_out, int out_size, void* d_ws, size_t ws_size,
                              hipStream_t stream) {
    const float* x_in = (const float*)d_in[0];
    const int*   eidx = (const int*)  d_in[1];
    const float* ew1  = (const float*)d_in[2];
    const float* eb1  = (const float*)d_in[3];
    const float* ew2  = (const float*)d_in[4];
    const float* eb2  = (const float*)d_in[5];
    const float* ng   = (const float*)d_in[6];
    const float* nb   = (const float*)d_in[7];
    const float* nw1  = (const float*)d_in[8];
    const float* nb1  = (const float*)d_in[9];
    const float* nw2  = (const float*)d_in[10];
    const float* nb2  = (const float*)d_in[11];
    const float* cw1  = (const float*)d_in[12];
    const float* cb1  = (const float*)d_in[13];
    const float* cw2  = (const float*)d_in[14];
    const float* cb2  = (const float*)d_in[15];
    float* out = (float*)d_out;

    char* ws = (char*)d_ws;
    size_t off = 0;
    auto alloc = [&](size_t bytes) { char* p = ws + off; off = (off + bytes + 255) & ~255ull; return p; };
    float* mi    = (float*)alloc((size_t)NN * MD * 4);
    float* mh    = (float*)alloc((size_t)NN * 3 * 4);
    float* eb1pf = (float*)alloc((size_t)3 * H1P * 4);
    float* w1lf  = (float*)alloc((size_t)3 * H1P * 4);
    char*  w1p   = alloc((size_t)3 * 1088 * 256);
    char*  w2b   = alloc((size_t)3 * 64 * 1088);
    char*  cw1b  = alloc((size_t)3 * 256 * 128);
    char*  nw1b  = alloc((size_t)3 * 256 * 384);
    char*  nw2b  = alloc((size_t)3 * 128 * 512);
    int* rowp = (int*) alloc((size_t)(NN + 1) * 4);
    int* eids = (int*) alloc((size_t)NE * 4);
    int* esrc = (int*) alloc((size_t)NE * 4);
    int* edst = (int*) alloc((size_t)NE * 4);
    int* cnt  = (int*) alloc((size_t)NN * 4);
    int* fillp= (int*) alloc((size_t)NN * 4);
    u16* gmij = (u16*)alloc((size_t)NE * 64 * 2);      // 41 MB
    float* gmh= (float*)alloc((size_t)NE * 4 * 4);     // 5.1 MB
    u16* Ybuf = (u16*)alloc((size_t)NN * 1088 * 2);    // 43.5 MB  (~102 MB total; R12 proved >=107 fits)

    prep_w1n<<<(3 * 1088 * 128 + 255) / 256, 256, 0, stream>>>(ew1, eb1, (u16*)w1p, eb1pf, w1lf);
    prep_w2 <<<(3 * 64 * H1P + 255) / 256, 256, 0, stream>>>(ew2, (u16*)w2b);
    prep_cw1<<<(3 * 256 * 64 + 255) / 256, 256, 0, stream>>>(cw1, (u16*)cw1b);
    prep_nw1<<<(3 * 256 * 192 + 255) / 256, 256, 0, stream>>>(nw1, (u16*)nw1b);
    prep_nw2<<<(3 * 128 * 256 + 255) / 256, 256, 0, stream>>>(nw2, (u16*)nw2b);

    hipMemsetAsync(cnt,  0, (size_t)NN * 4, stream);
    hipMemsetAsync(fillp,0, (size_t)NN * 4, stream);
    csr_hist<<<(NE + 255) / 256, 256, 0, stream>>>(eidx, cnt);
    csr_scan<<<1, 1024, 0, stream>>>(cnt, rowp);
    csr_fill<<<(NE + 255) / 256, 256, 0, stream>>>(eidx, rowp, fillp, eids);
    esort<<<(NE + 255) / 256, 256, 0, stream>>>(eidx, eids, esrc, edst);

    for (int l = 0; l < 3; ++l) {
        const float* xc = (l == 0) ? x_in : out;
        float*       xn = out;
        ygemm<<<dim3((NN + 127) / 128, 4), 256, 0, stream>>>(
            xc, w1p + (size_t)l * 1088 * 256, eb1pf + (size_t)l * H1P, Ybuf);
        edge_mfma2<<<NE / 128, 256, 0, stream>>>(
            xc, Ybuf, esrc, edst, w1lf + (size_t)l * H1P,
            w2b + (size_t)l * 64 * 1088, eb2 + (size_t)l * 64,
            cw1b + (size_t)l * 256 * 128, cb1 + (size_t)l * 256,
            cw2 + (size_t)l * 256, cb2 + l, gmij, gmh);
        reduce_mi<<<(NN + 7) / 8, 256, 0, stream>>>(gmij, gmh, rowp, mi, mh);
        node_mfma<<<(NN + 127) / 128, 256, 0, stream>>>(
            xc, mi, mh,
            ng + (size_t)l * F, nb + (size_t)l * F,
            nw1b + (size_t)l * 256 * 384, nb1 + (size_t)l * 256,
            nw2b + (size_t)l * 128 * 512, nb2 + (size_t)l * F,
            xn);
    }
}

// Round 16
// 813.689 us; speedup vs baseline: 1.6240x; 1.0082x over previous
//
#include <hip/hip_runtime.h>

typedef unsigned short u16;
typedef unsigned int   u32;
typedef __attribute__((ext_vector_type(2))) u32  u32x2;
typedef __attribute__((ext_vector_type(4))) u32  u32x4;
typedef __attribute__((ext_vector_type(8))) __bf16 bf16x8;
typedef __attribute__((ext_vector_type(4))) float  f32x4;

#define NN 20000
#define NE 320000
#define XD 131
#define F  128
#define MD 64
#define H1 514
#define H1P 544
#define NCH 17

#define LGKM0 asm volatile("s_waitcnt lgkmcnt(0)" ::: "memory")

__device__ __forceinline__ float silu(float a) {
    float e = __expf(-a);
    return a * __builtin_amdgcn_rcpf(1.0f + e);
}

__device__ __forceinline__ u16 f2bf(float f) {   // fp32 -> bf16 RNE
    u32 u = __builtin_bit_cast(u32, f);
    return (u16)((u + 0x7FFFu + ((u >> 16) & 1u)) >> 16);
}
__device__ __forceinline__ u16 bfc(float f) { return __builtin_bit_cast(u16, (__bf16)f); }
__device__ __forceinline__ u32 pk2(float a, float b) {
    return (u32)bfc(a) | ((u32)bfc(b) << 16);
}
__device__ __forceinline__ float blo(u32 u) { return __builtin_bit_cast(float, u << 16); }
__device__ __forceinline__ float bhi(u32 u) { return __builtin_bit_cast(float, u & 0xFFFF0000u); }
__device__ __forceinline__ bf16x8 mk8(u32 a, u32 b, u32 c, u32 d) {
    u32x4 t = {a, b, c, d};
    return __builtin_bit_cast(bf16x8, t);
}
__device__ __forceinline__ f32x4 mfma16(bf16x8 a, bf16x8 b, f32x4 c) {
    return __builtin_amdgcn_mfma_f32_16x16x32_bf16(a, b, c, 0, 0, 0);
}

// ---------------- weight prep ----------------

// w1p[l][n<1088][k<128] 256B rows. n<544: Ya cols (W1 rows 0..127); n>=544: Yb cols (rows 128..255).
__global__ void prep_w1n(const float* __restrict__ ew1, const float* __restrict__ eb1,
                         u16* __restrict__ w1p, float* __restrict__ eb1p, float* __restrict__ w1lf) {
    int i = blockIdx.x * 256 + threadIdx.x;
    if (i >= 3 * 1088 * 128) return;
    int k = i & 127;
    int n = (i >> 7) % 1088;
    int l = (i >> 7) / 1088;
    float v;
    if (n < H1P) v = (n < H1) ? ew1[(size_t)l * 257 * H1 + (size_t)k * H1 + n] : 0.f;
    else { int nn = n - H1P; v = (nn < H1) ? ew1[(size_t)l * 257 * H1 + (size_t)(128 + k) * H1 + nn] : 0.f; }
    w1p[(size_t)(l * 1088 + n) * 128 + k] = f2bf(v);
    if (k == 0 && n < H1P) {
        eb1p[l * H1P + n] = (n < H1) ? eb1[l * H1 + n] : 0.f;
        w1lf[l * H1P + n] = (n < H1) ? ew1[(size_t)l * 257 * H1 + (size_t)256 * H1 + n] : 0.f;
    }
}

__global__ void prep_w2(const float* __restrict__ ew2, u16* __restrict__ w2b) {
    int i = blockIdx.x * 256 + threadIdx.x;
    if (i >= 3 * 64 * H1P) return;
    int k = i % H1P;
    int n = (i / H1P) & 63;
    int l = i / (H1P * 64);
    float v = (k < H1) ? ew2[(size_t)l * H1 * 64 + (size_t)k * 64 + n] : 0.f;
    w2b[(size_t)(l * 64 + n) * H1P + k] = f2bf(v);
}

__global__ void prep_cw1(const float* __restrict__ cw1, u16* __restrict__ cw1b) {
    int i = blockIdx.x * 256 + threadIdx.x;
    if (i >= 3 * 256 * 64) return;
    int k = i & 63;
    int n = (i >> 6) & 255;
    int l = i >> 14;
    cw1b[(size_t)l * 16384 + n * 64 + k] = f2bf(cw1[(size_t)l * 16384 + k * 256 + n]);
}

__global__ void prep_nw1(const float* __restrict__ nw1, u16* __restrict__ nw1b) {
    int i = blockIdx.x * 256 + threadIdx.x;
    if (i >= 3 * 256 * 192) return;
    int k = i % 192;
    int n = (i / 192) & 255;
    int l = i / (192 * 256);
    nw1b[(size_t)(l * 256 + n) * 192 + k] = f2bf(nw1[(size_t)l * 192 * 256 + (size_t)k * 256 + n]);
}

__global__ void prep_nw2(const float* __restrict__ nw2, u16* __restrict__ nw2b) {
    int i = blockIdx.x * 256 + threadIdx.x;
    if (i >= 3 * 128 * 256) return;
    int k = i & 255;
    int n = (i >> 8) & 127;
    int l = i >> 15;
    nw2b[(size_t)(l * 128 + n) * 256 + k] = f2bf(nw2[(size_t)l * 256 * 128 + (size_t)k * 128 + n]);
}

// ---------------- Y precompute: Y[v][0:544]=X@W1a+b, Y[v][544:1088]=X@W1b ----------------

__global__ __launch_bounds__(256, 4) void ygemm(
    const float* __restrict__ xc, const char* __restrict__ w1p,
    const float* __restrict__ eb1p, u16* __restrict__ Y)
{
    const int tid = threadIdx.x;
    const int w = tid >> 6, l = tid & 63, lg = l >> 4, lc = l & 15;
    const int nb0 = blockIdx.x * 128 + w * 32;
    const int n0 = nb0 + lc, n1 = nb0 + 16 + lc;
    const bool v0 = n0 < NN, v1 = n1 < NN;
    const int m0 = v0 ? n0 : NN - 1, m1 = v1 ? n1 : NN - 1;

    bf16x8 BF[2][4];
    #pragma unroll
    for (int et = 0; et < 2; ++et) {
        const float* xr = xc + (size_t)(et ? m1 : m0) * XD + 3;
        #pragma unroll
        for (int kt = 0; kt < 4; ++kt) {
            const int k0 = kt * 32 + lg * 8;
            float4 a = *(const float4*)(xr + k0);
            float4 b = *(const float4*)(xr + k0 + 4);
            BF[et][kt] = mk8(pk2(a.x, a.y), pk2(a.z, a.w), pk2(b.x, b.y), pk2(b.z, b.w));
        }
    }

    const int t0 = blockIdx.y * 17;
    #pragma unroll 1
    for (int t = t0; t < t0 + 17; ++t) {
        bf16x8 AW[4];
        #pragma unroll
        for (int kt = 0; kt < 4; ++kt)
            AW[kt] = *(const bf16x8*)(w1p + (size_t)(t * 16 + lc) * 256 + kt * 64 + lg * 16);
        const int cb = t * 16 + lg * 4;
        f32x4 binit = {0.f, 0.f, 0.f, 0.f};
        if (cb < H1P) binit = *(const f32x4*)(eb1p + cb);
        f32x4 c0 = binit, c1 = binit;
        #pragma unroll
        for (int kt = 0; kt < 4; ++kt) {
            c0 = mfma16(AW[kt], BF[0][kt], c0);
            c1 = mfma16(AW[kt], BF[1][kt], c1);
        }
        u32x2 p0, p1;
        p0[0] = pk2(c0[0], c0[1]); p0[1] = pk2(c0[2], c0[3]);
        p1[0] = pk2(c1[0], c1[1]); p1[1] = pk2(c1[2], c1[3]);
        if (v0) *(u32x2*)(Y + (size_t)m0 * 1088 + cb) = p0;
        if (v1) *(u32x2*)(Y + (size_t)m1 * 1088 + cb) = p1;
    }
}

// ---------------- CSR build + edge sort (once per launch; graph constant) ----------------

__global__ void csr_hist(const int* __restrict__ eidx, int* __restrict__ cnt) {
    int e = blockIdx.x * 256 + threadIdx.x;
    if (e < NE) atomicAdd(&cnt[eidx[NE + e]], 1);
}

__global__ void csr_scan(const int* __restrict__ cnt, int* __restrict__ rowp) {
    __shared__ int ps[1024];
    const int t = threadIdx.x;
    const int base = t * 20;
    int loc[20];
    int s = 0;
    #pragma unroll
    for (int i = 0; i < 20; ++i) {
        const int idx = base + i;
        const int c = (idx < NN) ? cnt[idx] : 0;
        loc[i] = s;
        s += c;
    }
    ps[t] = s;
    __syncthreads();
    for (int off = 1; off < 1024; off <<= 1) {
        int v = (t >= off) ? ps[t - off] : 0;
        __syncthreads();
        ps[t] += v;
        __syncthreads();
    }
    const int segbase = (t > 0) ? ps[t - 1] : 0;
    #pragma unroll
    for (int i = 0; i < 20; ++i) {
        const int idx = base + i;
        if (idx < NN) rowp[idx] = segbase + loc[i];
    }
    if (t == 1023) rowp[NN] = ps[1023];
}

__global__ void csr_fill(const int* __restrict__ eidx, const int* __restrict__ rowp,
                         int* __restrict__ fill, int* __restrict__ eids) {
    int e = blockIdx.x * 256 + threadIdx.x;
    if (e >= NE) return;
    const int d = eidx[NE + e];
    const int pos = atomicAdd(&fill[d], 1);
    eids[rowp[d] + pos] = e;
}

__global__ void esort(const int* __restrict__ eidx, const int* __restrict__ eids,
                      int* __restrict__ esrc, int* __restrict__ edst) {
    int j = blockIdx.x * 256 + threadIdx.x;
    if (j >= NE) return;
    const int e = eids[j];
    esrc[j] = eidx[e];
    edst[j] = eidx[NE + e];
}

// ---------------- edge kernel (R15, unchanged — passing at 175 us) ----------------

__global__ __launch_bounds__(256, 6) void edge_mfma2(
    const float* __restrict__ x, const u16* __restrict__ Y,
    const int* __restrict__ esrc, const int* __restrict__ edst,
    const float* __restrict__ w1lf,
    const char* __restrict__ w2b, const float* __restrict__ eb2,
    const char* __restrict__ cw1b, const float* __restrict__ cb1,
    const float* __restrict__ cw2, const float* __restrict__ cb2,
    u16* __restrict__ gmij, float* __restrict__ gmh)
{
    __shared__ __align__(16) char LDS[19456];   // [0,17408) MJ per-wave 4352B; [17408,19456) RDS
    const int tid = threadIdx.x;
    const int w = tid >> 6, l = tid & 63, lg = l >> 4, lc = l & 15;
    const int ebase = blockIdx.x * 128 + w * 32;
    char*  MJ  = LDS + w * 4352;
    float* RDS = (float*)(LDS + 17408);

    if (l < 32) {
        const int e = ebase + l;
        const int s = esrc[e], d = edst[e];
        const float ax = x[(size_t)s * XD + 0] - x[(size_t)d * XD + 0];
        const float ay = x[(size_t)s * XD + 1] - x[(size_t)d * XD + 1];
        const float az = x[(size_t)s * XD + 2] - x[(size_t)d * XD + 2];
        f32x4 v = {ax, ay, az, ax * ax + ay * ay + az * az};
        *(f32x4*)(RDS + (w * 32 + l) * 4) = v;
    }
    const int s0 = esrc[ebase + lc],      d0 = edst[ebase + lc];
    const int s1 = esrc[ebase + 16 + lc], d1 = edst[ebase + 16 + lc];
    LGKM0;
    const float rd0 = RDS[(w * 32 + lc) * 4 + 3];
    const float rd1 = RDS[(w * 32 + 16 + lc) * 4 + 3];

    f32x4 c2[2][4];
    #pragma unroll
    for (int nt = 0; nt < 4; ++nt) {
        const float b = eb2[nt * 16 + lc];
        c2[0][nt] = (f32x4){b, b, b, b};
        c2[1][nt] = (f32x4){b, b, b, b};
    }

    #pragma unroll 1
    for (int ch = 0; ch < NCH; ++ch) {
        const int cb = ch * 32 + lg * 8;
        u32x4 ya0 = *(const u32x4*)(Y + (size_t)d0 * 1088 + cb);
        u32x4 yb0 = *(const u32x4*)(Y + (size_t)s0 * 1088 + 544 + cb);
        u32x4 ya1 = *(const u32x4*)(Y + (size_t)d1 * 1088 + cb);
        u32x4 yb1 = *(const u32x4*)(Y + (size_t)s1 * 1088 + 544 + cb);
        f32x4 wlA = *(const f32x4*)(w1lf + cb);
        f32x4 wlB = *(const f32x4*)(w1lf + cb + 4);
        u32 pk0[4], pk1[4];
        #pragma unroll
        for (int j = 0; j < 4; ++j) {
            const float wa = (j < 2) ? wlA[2 * j]     : wlB[2 * j - 4];
            const float wb = (j < 2) ? wlA[2 * j + 1] : wlB[2 * j - 3];
            {
                const float a0 = blo(ya0[j]) + blo(yb0[j]) + rd0 * wa;
                const float a1 = bhi(ya0[j]) + bhi(yb0[j]) + rd0 * wb;
                pk0[j] = pk2(silu(a0), silu(a1));
            }
            {
                const float a0 = blo(ya1[j]) + blo(yb1[j]) + rd1 * wa;
                const float a1 = bhi(ya1[j]) + bhi(yb1[j]) + rd1 * wb;
                pk1[j] = pk2(silu(a0), silu(a1));
            }
        }
        bf16x8 A20 = mk8(pk0[0], pk0[1], pk0[2], pk0[3]);
        bf16x8 A21 = mk8(pk1[0], pk1[1], pk1[2], pk1[3]);
        #pragma unroll
        for (int nt = 0; nt < 4; ++nt) {
            bf16x8 Bw = __builtin_bit_cast(bf16x8,
                *(const u32x4*)(w2b + (size_t)(nt * 16 + lc) * 1088 + ch * 64 + lg * 16));
            c2[0][nt] = mfma16(A20, Bw, c2[0][nt]);
            c2[1][nt] = mfma16(A21, Bw, c2[1][nt]);
        }
    }

    #pragma unroll
    for (int mt = 0; mt < 2; ++mt)
        #pragma unroll
        for (int nt = 0; nt < 4; ++nt)
            #pragma unroll
            for (int r = 0; r < 4; ++r) {
                const float v = silu(c2[mt][nt][r]);
                const int rowl = mt * 16 + lg * 4 + r;
                const int col  = nt * 16 + lc;
                *(u16*)(MJ + rowl * 136 + col * 2) = bfc(v);
            }
    LGKM0;

    {
        u16* grow = gmij + (size_t)ebase * 64;
        #pragma unroll
        for (int i = 0; i < 4; ++i) {
            const int row = i * 8 + (l >> 3);
            u32x4 v = *(u32x4*)(MJ + row * 136 + (l & 7) * 16);
            *(u32x4*)(grow + (size_t)row * 64 + (l & 7) * 8) = v;
        }
    }

    bf16x8 A3[2][2];
    #pragma unroll
    for (int mt = 0; mt < 2; ++mt)
        #pragma unroll
        for (int kt = 0; kt < 2; ++kt)
            A3[mt][kt] = *(bf16x8*)(MJ + (mt * 16 + lc) * 136 + kt * 64 + lg * 16);

    float pw[2][4] = {{0.f, 0.f, 0.f, 0.f}, {0.f, 0.f, 0.f, 0.f}};
    #pragma unroll 4
    for (int ct3 = 0; ct3 < 16; ++ct3) {
        const int col = ct3 * 16 + lc;
        const float b = cb1[col];
        f32x4 c30 = {b, b, b, b}, c31 = {b, b, b, b};
        #pragma unroll
        for (int kt = 0; kt < 2; ++kt) {
            bf16x8 B = __builtin_bit_cast(bf16x8,
                *(const u32x4*)(cw1b + (size_t)col * 128 + kt * 64 + lg * 16));
            c30 = mfma16(A3[0][kt], B, c30);
            c31 = mfma16(A3[1][kt], B, c31);
        }
        const float w2v = cw2[col];
        #pragma unroll
        for (int r = 0; r < 4; ++r) {
            pw[0][r] = fmaf(silu(c30[r]), w2v, pw[0][r]);
            pw[1][r] = fmaf(silu(c31[r]), w2v, pw[1][r]);
        }
    }
    #pragma unroll
    for (int m = 1; m < 16; m <<= 1)
        #pragma unroll
        for (int mt = 0; mt < 2; ++mt)
            #pragma unroll
            for (int r = 0; r < 4; ++r)
                pw[mt][r] += __shfl_xor(pw[mt][r], m, 64);

    const float cb2v = cb2[0];
    if (lc < 3) {
        #pragma unroll
        for (int mt = 0; mt < 2; ++mt)
            #pragma unroll
            for (int r = 0; r < 4; ++r) {
                const int rowl = mt * 16 + lg * 4 + r;
                const float cwv = pw[mt][r] + cb2v;
                gmh[(size_t)(ebase + rowl) * 4 + lc] = cwv * RDS[(w * 32 + rowl) * 4 + lc];
            }
    }
}

// ---------------- node kernel: LN + fused segment-sum + MLP via MFMA ----------------
// m_i fragments built by summing gmij rows [rowp[n], rowp[n+1]) directly (reduce_mi fused);
// coors tail sums gmh inline. Block's segment rows are contiguous -> L2-resident.

__global__ __launch_bounds__(256, 2) void node_mfma(
    const float* __restrict__ xc,
    const u16* __restrict__ gmij, const float* __restrict__ gmh, const int* __restrict__ rowp,
    const float* __restrict__ ng, const float* __restrict__ nb,
    const char* __restrict__ nw1b, const float* __restrict__ nb1,
    const char* __restrict__ nw2b, const float* __restrict__ nb2,
    float* __restrict__ xn)
{
    __shared__ __align__(16) char LDS[4 * 4352];
    const int tid = threadIdx.x;
    const int w = tid >> 6, l = tid & 63, lg = l >> 4, lc = l & 15;
    char* HB = LDS + w * 4352;
    const int nb0 = blockIdx.x * 128 + w * 32;

    int nodes[2]; bool valid[2];
    #pragma unroll
    for (int et = 0; et < 2; ++et) {
        int n = nb0 + et * 16 + lc;
        valid[et] = (n < NN);
        nodes[et] = valid[et] ? n : (NN - 1);
    }

    bf16x8 BF[2][6];
    #pragma unroll
    for (int et = 0; et < 2; ++et) {
        const float* xr = xc + (size_t)nodes[et] * XD + 3;
        float v[4][8];
        float s = 0.f, q = 0.f;
        #pragma unroll
        for (int kt = 0; kt < 4; ++kt) {
            const int k0 = kt * 32 + lg * 8;
            #pragma unroll
            for (int j = 0; j < 8; ++j) {
                const float t = xr[k0 + j];
                v[kt][j] = t; s += t; q = fmaf(t, t, q);
            }
        }
        s += __shfl_xor(s, 16, 64); s += __shfl_xor(s, 32, 64);
        q += __shfl_xor(q, 16, 64); q += __shfl_xor(q, 32, 64);
        const float mu = s * (1.f / 128.f);
        const float rs = rsqrtf(q * (1.f / 128.f) - mu * mu + 1e-5f);
        #pragma unroll
        for (int kt = 0; kt < 4; ++kt) {
            const int k0 = kt * 32 + lg * 8;
            float4 g0 = *(const float4*)(ng + k0), g1 = *(const float4*)(ng + k0 + 4);
            float4 b0 = *(const float4*)(nb + k0), b1 = *(const float4*)(nb + k0 + 4);
            const u32 u0 = pk2((v[kt][0] - mu) * rs * g0.x + b0.x, (v[kt][1] - mu) * rs * g0.y + b0.y);
            const u32 u1 = pk2((v[kt][2] - mu) * rs * g0.z + b0.z, (v[kt][3] - mu) * rs * g0.w + b0.w);
            const u32 u2 = pk2((v[kt][4] - mu) * rs * g1.x + b1.x, (v[kt][5] - mu) * rs * g1.y + b1.y);
            const u32 u3 = pk2((v[kt][6] - mu) * rs * g1.z + b1.z, (v[kt][7] - mu) * rs * g1.w + b1.w);
            BF[et][kt] = mk8(u0, u1, u2, u3);
        }
        // ---- fused m_i segment sum over CSR rows (was reduce_mi) ----
        {
            const int n = nodes[et];
            const int jb = rowp[n], je = rowp[n + 1];
            float a0[8] = {0,0,0,0,0,0,0,0};   // cols lg*8..+7        (kt2=0)
            float a1[8] = {0,0,0,0,0,0,0,0};   // cols 32+lg*8..+7     (kt2=1)
            for (int j = jb; j < je; ++j) {
                const u16* gr = gmij + (size_t)j * 64;
                u32x4 q0 = *(const u32x4*)(gr + lg * 8);
                u32x4 q1 = *(const u32x4*)(gr + 32 + lg * 8);
                #pragma unroll
                for (int i = 0; i < 4; ++i) {
                    a0[2*i]   += blo(q0[i]); a0[2*i+1] += bhi(q0[i]);
                    a1[2*i]   += blo(q1[i]); a1[2*i+1] += bhi(q1[i]);
                }
            }
            BF[et][4] = mk8(pk2(a0[0],a0[1]), pk2(a0[2],a0[3]), pk2(a0[4],a0[5]), pk2(a0[6],a0[7]));
            BF[et][5] = mk8(pk2(a1[0],a1[1]), pk2(a1[2],a1[3]), pk2(a1[4],a1[5]), pk2(a1[6],a1[7]));
        }
    }

    f32x4 a2[8][2];
    #pragma unroll
    for (int ct2 = 0; ct2 < 8; ++ct2) {
        f32x4 b = *(const f32x4*)(nb2 + ct2 * 16 + lg * 4);
        a2[ct2][0] = b; a2[ct2][1] = b;
    }

    #pragma unroll 1
    for (int g = 0; g < 4; ++g) {
        f32x4 a1[4][2];
        #pragma unroll
        for (int ct = 0; ct < 4; ++ct) {
            f32x4 b = *(const f32x4*)(nb1 + g * 64 + ct * 16 + lg * 4);
            a1[ct][0] = b; a1[ct][1] = b;
        }
        #pragma unroll
        for (int ct = 0; ct < 4; ++ct)
            #pragma unroll
            for (int kt = 0; kt < 6; ++kt) {
                bf16x8 Aw = __builtin_bit_cast(bf16x8, *(const u32x4*)(
                    nw1b + (size_t)(g * 64 + ct * 16 + lc) * 384 + kt * 64 + lg * 16));
                a1[ct][0] = mfma16(Aw, BF[0][kt], a1[ct][0]);
                a1[ct][1] = mfma16(Aw, BF[1][kt], a1[ct][1]);
            }
        #pragma unroll
        for (int ct = 0; ct < 4; ++ct)
            #pragma unroll
            for (int et = 0; et < 2; ++et) {
                f32x4 c = a1[ct][et];
                u32 v0 = pk2(silu(c[0]), silu(c[1]));
                u32 v1 = pk2(silu(c[2]), silu(c[3]));
                *(u32*)(HB + (et * 16 + lc) * 136 + ct * 32 + lg * 8) = v0;
                *(u32*)(HB + (et * 16 + lc) * 136 + ct * 32 + lg * 8 + 4) = v1;
            }
        LGKM0;
        __builtin_amdgcn_sched_barrier(0);
        bf16x8 B2[2][2];
        #pragma unroll
        for (int et = 0; et < 2; ++et)
            #pragma unroll
            for (int kt2 = 0; kt2 < 2; ++kt2) {
                u32 a = *(u32*)(HB + (et * 16 + lc) * 136 + kt2 * 64 + lg * 16);
                u32 b = *(u32*)(HB + (et * 16 + lc) * 136 + kt2 * 64 + lg * 16 + 4);
                u32 c = *(u32*)(HB + (et * 16 + lc) * 136 + kt2 * 64 + lg * 16 + 8);
                u32 d = *(u32*)(HB + (et * 16 + lc) * 136 + kt2 * 64 + lg * 16 + 12);
                B2[et][kt2] = mk8(a, b, c, d);
            }
        #pragma unroll
        for (int ct2 = 0; ct2 < 8; ++ct2)
            #pragma unroll
            for (int kt2 = 0; kt2 < 2; ++kt2) {
                bf16x8 Aw = __builtin_bit_cast(bf16x8, *(const u32x4*)(
                    nw2b + (size_t)(ct2 * 16 + lc) * 512 + (g * 64 + kt2 * 32 + lg * 8) * 2));
                a2[ct2][0] = mfma16(Aw, B2[0][kt2], a2[ct2][0]);
                a2[ct2][1] = mfma16(Aw, B2[1][kt2], a2[ct2][1]);
            }
        LGKM0;
        __builtin_amdgcn_sched_barrier(0);
    }

    #pragma unroll
    for (int et = 0; et < 2; ++et) {
        if (!valid[et]) continue;
        const size_t nr = (size_t)nodes[et] * XD;
        #pragma unroll
        for (int ct2 = 0; ct2 < 8; ++ct2)
            #pragma unroll
            for (int r = 0; r < 4; ++r) {
                const int col = ct2 * 16 + lg * 4 + r;
                xn[nr + 3 + col] = a2[ct2][et][r] + xc[nr + 3 + col];
            }
    }
    // coors update: fused gmh segment sum (was mh roundtrip)
    for (int idx = tid; idx < 384; idx += 256) {
        const int n = blockIdx.x * 128 + idx / 3;
        const int d = idx - (idx / 3) * 3;
        if (n < NN) {
            const int jb = rowp[n], je = rowp[n + 1];
            float m = 0.f;
            for (int j = jb; j < je; ++j) m += gmh[(size_t)j * 4 + d];
            xn[(size_t)n * XD + d] = xc[(size_t)n * XD + d] + m;
        }
    }
}

// ---------------- launch ----------------

extern "C" void kernel_launch(void* const* d_in, const int* in_sizes, int n_in,
                              void* d_out, int out_size, void* d_ws, size_t ws_size,
                              hipStream_t stream) {
    const float* x_in = (const float*)d_in[0];
    const int*   eidx = (const int*)  d_in[1];
    const float* ew1  = (const float*)d_in[2];
    const float* eb1  = (const float*)d_in[3];
    const float* ew2  = (const float*)d_in[4];
    const float* eb2  = (const float*)d_in[5];
    const float* ng   = (const float*)d_in[6];
    const float* nb   = (const float*)d_in[7];
    const float* nw1  = (const float*)d_in[8];
    const float* nb1  = (const float*)d_in[9];
    const float* nw2  = (const float*)d_in[10];
    const float* nb2  = (const float*)d_in[11];
    const float* cw1  = (const float*)d_in[12];
    const float* cb1  = (const float*)d_in[13];
    const float* cw2  = (const float*)d_in[14];
    const float* cb2  = (const float*)d_in[15];
    float* out = (float*)d_out;

    char* ws = (char*)d_ws;
    size_t off = 0;
    auto alloc = [&](size_t bytes) { char* p = ws + off; off = (off + bytes + 255) & ~255ull; return p; };
    float* eb1pf = (float*)alloc((size_t)3 * H1P * 4);
    float* w1lf  = (float*)alloc((size_t)3 * H1P * 4);
    char*  w1p   = alloc((size_t)3 * 1088 * 256);
    char*  w2b   = alloc((size_t)3 * 64 * 1088);
    char*  cw1b  = alloc((size_t)3 * 256 * 128);
    char*  nw1b  = alloc((size_t)3 * 256 * 384);
    char*  nw2b  = alloc((size_t)3 * 128 * 512);
    int* rowp = (int*) alloc((size_t)(NN + 1) * 4);
    int* eids = (int*) alloc((size_t)NE * 4);
    int* esrc = (int*) alloc((size_t)NE * 4);
    int* edst = (int*) alloc((size_t)NE * 4);
    int* cnt  = (int*) alloc((size_t)NN * 4);
    int* fillp= (int*) alloc((size_t)NN * 4);
    u16* gmij = (u16*)alloc((size_t)NE * 64 * 2);      // 41 MB
    float* gmh= (float*)alloc((size_t)NE * 4 * 4);     // 5.1 MB
    u16* Ybuf = (u16*)alloc((size_t)NN * 1088 * 2);    // 43.5 MB

    prep_w1n<<<(3 * 1088 * 128 + 255) / 256, 256, 0, stream>>>(ew1, eb1, (u16*)w1p, eb1pf, w1lf);
    prep_w2 <<<(3 * 64 * H1P + 255) / 256, 256, 0, stream>>>(ew2, (u16*)w2b);
    prep_cw1<<<(3 * 256 * 64 + 255) / 256, 256, 0, stream>>>(cw1, (u16*)cw1b);
    prep_nw1<<<(3 * 256 * 192 + 255) / 256, 256, 0, stream>>>(nw1, (u16*)nw1b);
    prep_nw2<<<(3 * 128 * 256 + 255) / 256, 256, 0, stream>>>(nw2, (u16*)nw2b);

    hipMemsetAsync(cnt,  0, (size_t)NN * 4, stream);
    hipMemsetAsync(fillp,0, (size_t)NN * 4, stream);
    csr_hist<<<(NE + 255) / 256, 256, 0, stream>>>(eidx, cnt);
    csr_scan<<<1, 1024, 0, stream>>>(cnt, rowp);
    csr_fill<<<(NE + 255) / 256, 256, 0, stream>>>(eidx, rowp, fillp, eids);
    esort<<<(NE + 255) / 256, 256, 0, stream>>>(eidx, eids, esrc, edst);

    for (int l = 0; l < 3; ++l) {
        const float* xc = (l == 0) ? x_in : out;
        float*       xn = out;
        ygemm<<<dim3((NN + 127) / 128, 4), 256, 0, stream>>>(
            xc, w1p + (size_t)l * 1088 * 256, eb1pf + (size_t)l * H1P, Ybuf);
        edge_mfma2<<<NE / 128, 256, 0, stream>>>(
            xc, Ybuf, esrc, edst, w1lf + (size_t)l * H1P,
            w2b + (size_t)l * 64 * 1088, eb2 + (size_t)l * 64,
            cw1b + (size_t)l * 256 * 128, cb1 + (size_t)l * 256,
            cw2 + (size_t)l * 256, cb2 + l, gmij, gmh);
        node_mfma<<<(NN + 127) / 128, 256, 0, stream>>>(
            xc, gmij, gmh, rowp,
            ng + (size_t)l * F, nb + (size_t)l * F,
            nw1b + (size_t)l * 256 * 384, nb1 + (size_t)l * 256,
            nw2b + (size_t)l * 128 * 512, nb2 + (size_t)l * F,
            xn);
    }
}